// Round 10
// baseline (136.688 us; speedup 1.0000x reference)
//
#include <hip/hip_runtime.h>
#include <math.h>
#include <stdint.h>

#define V_PTS 8192
#define NQ    1024
#define TWO_PI 6.283185307179586f
#define INV_SQRT2 0.70710678118654752f

typedef float floatx4 __attribute__((ext_vector_type(4)));
typedef short bf16x8 __attribute__((ext_vector_type(8)));
typedef _Float16 h16x2 __attribute__((ext_vector_type(2)));

union FragU { uint32_t u[4]; bf16x8 s; };
union WU { uint32_t u; h16x2 h; };

__device__ __forceinline__ float gelu_erf(float a) {
  return 0.5f * a * (1.0f + erff(a * INV_SQRT2));
}
__device__ __forceinline__ void gload_lds16(const void* g, void* l) {
  __builtin_amdgcn_global_load_lds(
      (const __attribute__((address_space(1))) void*)g,
      (__attribute__((address_space(3))) void*)l, 16, 0, 0);
}
// pack f32 -> (bf16_hi << 16) | bf16_lo(residual), both truncated
__device__ __forceinline__ uint32_t pack_split(float f) {
  const uint32_t fu = __float_as_uint(f);
  const float lf = f - __uint_as_float(fu & 0xFFFF0000u);
  return __builtin_amdgcn_perm(fu, __float_as_uint(lf), 0x07060302u);
}
__device__ __forceinline__ void buildfrag(const uint4& w01, const uint4& w23,
                                          FragU& Fh, FragU& Fl) {
  const uint32_t w[8] = {w01.x, w01.y, w01.z, w01.w, w23.x, w23.y, w23.z, w23.w};
#pragma unroll
  for (int t = 0; t < 4; ++t) {
    Fh.u[t] = __builtin_amdgcn_perm(w[2 * t + 1], w[2 * t], 0x07060302u);
    Fl.u[t] = __builtin_amdgcn_perm(w[2 * t + 1], w[2 * t], 0x05040100u);
  }
}
#if __has_builtin(__builtin_amdgcn_fdot2)
#define FDOT2(G, W, ACC) ACC = __builtin_amdgcn_fdot2(G, W, ACC, false)
#else
#define FDOT2(G, W, ACC) ACC += (float)(G.x) * (float)(W.x) + (float)(G.y) * (float)(W.y)
#endif

// ---------------- Kernel A: weight fold (17 blocks) + x pack (1024 blocks) ----------------
__global__ __launch_bounds__(256) void aux_kernel(
    const float* __restrict__ x, const float* __restrict__ Wl,
    const float* __restrict__ bl, const float* __restrict__ W2,
    const float* __restrict__ filt,
    uint32_t* __restrict__ xs, uint32_t* __restrict__ W2pp,
    float* __restrict__ W2b) {
  const int bid = blockIdx.x, tid = threadIdx.x;
  if (bid >= 17) {
    const int b = bid - 17;
#pragma unroll
    for (int u = 0; u < 4; ++u) {
      const int i4 = (b * 4 + u) * 256 + tid;
      const float4 f = ((const float4*)x)[i4];
      uint4 o;
      o.x = pack_split(f.x); o.y = pack_split(f.y);
      o.z = pack_split(f.z); o.w = pack_split(f.w);
      ((uint4*)xs)[i4] = o;
    }
    return;
  }
  __shared__ float sWl[1024];
  for (int i = tid; i < 1024; i += 256) sWl[i] = Wl[i];
  __syncthreads();
  const int j2 = bid;                       // 0..16
  const float* srca = (j2 < 16) ? (W2 + (2 * j2) * 512) : filt;   // row 2*j2 (32 -> filt)
  const float* srcb = W2 + (2 * j2 + 1) * 512;                    // valid only j2<16
#pragma unroll
  for (int pass = 0; pass < 2; ++pass) {
    const int r = pass * 256 + tid;         // 0..511
    const int cp = r >> 4, d = r & 15;
    float w0 = 0.0f, w1 = 0.0f;
#pragma unroll
    for (int c = 0; c < 32; ++c) {
      const float wl = sWl[cp * 32 + c];
      w0 = fmaf(wl, srca[(c << 4) + d], w0);
      if (j2 < 16) w1 = fmaf(wl, srcb[(c << 4) + d], w1);
    }
    WU cv;
    cv.h.x = (_Float16)w0; cv.h.y = (_Float16)w1;   // RNE; w1=0 for j2==16
    W2pp[j2 * 512 + r] = cv.u;
  }
  if (tid < 32) {
    const int j = 2 * j2 + (tid >> 4), d = tid & 15;
    if (j <= 32) {
      const float* src = (j < 32) ? (W2 + (j << 9)) : filt;
      float acc = 0.0f;
#pragma unroll
      for (int c = 0; c < 32; ++c) acc = fmaf(bl[c], src[(c << 4) + d], acc);
      W2b[j * 16 + d] = acc;
    }
  }
}

// ---------------- Kernel B: per-query selection + packed/swizzled H generation ----------------
__global__ __launch_bounds__(256) void sel_kernel(
    const float* __restrict__ pos, const float* __restrict__ qpos,
    const float* __restrict__ qmw, const float* __restrict__ qmo,
    const float* __restrict__ Brff, const float* __restrict__ W1,
    const float* __restrict__ b1, const float* __restrict__ bout,
    const float* __restrict__ W2b,
    int* __restrict__ seli_ws, uint32_t* __restrict__ Hc_ws,
    uint32_t* __restrict__ kdp_ws, float* __restrict__ ybias_ws,
    float* __restrict__ out) {
  __shared__ float s_W1[1024];
  __shared__ __align__(16) float s_H2f[33 * 128];   // [j][k]
  __shared__ int   s_seli[128];
  __shared__ float s_sele[128];
  __shared__ float s_kd[128];
  __shared__ float s_small[128];
  __shared__ int   s_redi[2][4];
  __shared__ unsigned s_redu[4];
  __shared__ int   s_wsum[4];
  __shared__ float s_red2[2];
  __shared__ float s_hsum[32];

  const int tid  = threadIdx.x;
  const int q    = blockIdx.x;
  const int lane = tid & 63;
  const int wv   = tid >> 6;

  for (int i = tid; i < 1024; i += 256) s_W1[i] = W1[i];
  if (tid < 32) {
    s_small[tid]      = Brff[tid];
    s_small[32 + tid] = b1[tid];
    s_small[64 + tid] = qmw[q * 32 + tid];
    s_small[96 + tid] = qmo[q * 32 + tid];
  }

  const float qx = qpos[2 * q], qy = qpos[2 * q + 1];

  // ---- Phase 1: squared torus distances as monotone uint bits
  unsigned u[32];
  unsigned umin = 0xFFFFFFFFu;
#pragma unroll
  for (int i = 0; i < 32; ++i) {
    const int v = i * 256 + tid;
    const float2 p = *(const float2*)(pos + 2 * v);
    float dx = qx - p.x + 0.5f; dx -= floorf(dx); dx -= 0.5f;
    float dy = qy - p.y + 0.5f; dy -= floorf(dy); dy -= 0.5f;
    const float e = dx * dx + dy * dy;
    u[i] = __float_as_uint(e);
    umin = min(umin, u[i]);
  }
#pragma unroll
  for (int off = 32; off > 0; off >>= 1) {
    unsigned o = (unsigned)__shfl_down((int)umin, off);
    umin = min(umin, o);
  }
  if (lane == 0) s_redu[wv] = umin;
  __syncthreads();
  const unsigned uminAll = min(min(s_redu[0], s_redu[1]), min(s_redu[2], s_redu[3]));

  // ---- Phase 2: binary search for 128th-smallest (ballot count, 1 barrier/iter)
  unsigned lo = uminAll, hi = 0x3F000001u;
  int itp = 0;
  while (lo < hi) {
    const unsigned mid = lo + ((hi - lo) >> 1);
    int c = 0;
#pragma unroll
    for (int i = 0; i < 32; ++i)
      c += (int)__popcll(__ballot(u[i] <= mid));
    if (lane == 0) s_redi[itp][wv] = c;
    __syncthreads();
    const int tot = s_redi[itp][0] + s_redi[itp][1] + s_redi[itp][2] + s_redi[itp][3];
    itp ^= 1;
    if (tot >= 128) hi = mid; else lo = mid + 1;
  }
  const unsigned T = lo;

  // ---- Phase 3: deterministic compaction (shfl scan)
  int clt = 0, ceq = 0;
#pragma unroll
  for (int i = 0; i < 32; ++i) { clt += (u[i] < T) ? 1 : 0; ceq += (u[i] == T) ? 1 : 0; }
  int sv = clt | (ceq << 16);
#pragma unroll
  for (int off = 1; off < 64; off <<= 1) {
    const int n = __shfl_up(sv, off, 64);
    if (lane >= off) sv += n;
  }
  if (lane == 63) s_wsum[wv] = sv;
  __syncthreads();
  int add = 0;
#pragma unroll
  for (int w = 0; w < 4; ++w) add += (w < wv) ? s_wsum[w] : 0;
  const int incl   = sv + add;
  const int totAll = s_wsum[0] + s_wsum[1] + s_wsum[2] + s_wsum[3];
  const int totLt  = totAll & 0xFFFF;
  int plt = (incl & 0xFFFF) - clt;
  int peq = totLt + ((incl >> 16) - ceq);
#pragma unroll
  for (int i = 0; i < 32; ++i) {
    const int v = i * 256 + tid;
    if (u[i] < T)        { s_seli[plt] = v; s_sele[plt] = __uint_as_float(u[i]); ++plt; }
    else if (u[i] == T)  { if (peq < 128) { s_seli[peq] = v; s_sele[peq] = __uint_as_float(u[i]); } ++peq; }
  }
  __syncthreads();

  // ---- Phase 4: k_dist softmax
  const float eminf = __uint_as_float(uminAll);
  const float emaxf = __uint_as_float(T);
  float wexp = 0.0f;
  if (tid < 128) {
    const float nrm = (s_sele[tid] - eminf) / ((emaxf - eminf) + 1e-8f);
    wexp = expf(-nrm);
  }
  if (wv < 2) {
    float ws = wexp;
#pragma unroll
    for (int m = 1; m < 64; m <<= 1) ws += __shfl_xor(ws, m, 64);
    if (lane == 0) s_red2[wv] = ws;
  }
  __syncthreads();
  const float wsum = s_red2[0] + s_red2[1];
  if (tid < 128) s_kd[tid] = wexp / wsum;
  __syncthreads();

  // ---- Phase 5: RFF -> modulated MLP -> s_H2f[j][k]
  {
    const int k = tid >> 1, hh = tid & 1;
    const int v = s_seli[k];
    const float2 p = *(const float2*)(pos + 2 * v);
    float dx = qx - p.x + 0.5f; dx -= floorf(dx); dx -= 0.5f;
    float dy = qy - p.y + 0.5f; dy -= floorf(dy); dy -= 0.5f;
    float sn[16], cs[16];
#pragma unroll
    for (int i = 0; i < 16; ++i) {
      const float pr = TWO_PI * (dx * s_small[i] + dy * s_small[16 + i]);
      sn[i] = sinf(pr); cs[i] = cosf(pr);
    }
    const float kdv = s_kd[k];
#pragma unroll
    for (int jj = 0; jj < 16; ++jj) {
      const int j = hh * 16 + jj;
      float s = s_small[32 + j];
#pragma unroll
      for (int r = 0; r < 16; ++r) s = fmaf(sn[r], s_W1[r * 32 + j], s);
#pragma unroll
      for (int r = 0; r < 16; ++r) s = fmaf(cs[r], s_W1[(16 + r) * 32 + j], s);
      const float a = s * s_small[64 + j] + s_small[96 + j];
      s_H2f[j * 128 + k] = kdv * gelu_erf(a);
    }
    if (hh == 0) s_H2f[32 * 128 + k] = kdv;
  }
  __syncthreads();

  // ---- outputs
  if (tid < 128) seli_ws[q * 128 + tid] = s_seli[tid];
  // Hc: [ch][j 0..31][pos5], content swizzled: pos5 holds k = ch*32 + (pos5 ^ ((j&7)<<2))
  for (int idx = tid; idx < 4096; idx += 256) {
    const int ch = idx >> 10, j = (idx >> 5) & 31, p5 = idx & 31;
    const int k = ch * 32 + (p5 ^ ((j & 7) << 2));
    Hc_ws[(size_t)q * 4096 + idx] = pack_split(s_H2f[j * 128 + k]);
  }
  if (tid < 128) kdp_ws[q * 128 + tid] = pack_split(s_H2f[32 * 128 + tid]);
  {
    const int j = tid >> 3, m = tid & 7;
    float s = 0.0f;
#pragma unroll
    for (int i = 0; i < 16; ++i) s += s_H2f[j * 128 + m + i * 8];
    s += __shfl_xor(s, 1, 64); s += __shfl_xor(s, 2, 64); s += __shfl_xor(s, 4, 64);
    if (m == 0) s_hsum[j] = s;
  }
  __syncthreads();
  if (tid < 16) {
    float b = bout[tid] + W2b[32 * 16 + tid];   // sum(kd) = 1
#pragma unroll
    for (int j = 0; j < 32; ++j) b = fmaf(s_hsum[j], W2b[j * 16 + tid], b);
    ybias_ws[q * 16 + tid] = b;
  }
  if (tid < 2) out[16 * NQ * 16 + q * 2 + tid] = qpos[q * 2 + tid];
}

// ---------------- Kernel C: barrier-free MFMA gather-GEMM ----------------
// X gathered DIRECTLY global->VGPR (no LDS, no in-loop barriers): per instr the
// 16 m16-lanes read 64B contiguous, 4 grp-rows = 4 segments. 1-chunk-ahead
// software pipeline with NAMED reg buffers (runtime-indexed arrays spill, rule 20).
// H via prologue-only DMA (r7 proven). Plain __launch_bounds__(256) (r3 lesson).
__global__ __launch_bounds__(256) void main_kernel(
    const uint32_t* __restrict__ xs, const int* __restrict__ seli_ws,
    const uint32_t* __restrict__ Hc, const uint32_t* __restrict__ kdp,
    const float* __restrict__ ybias_ws, const uint32_t* __restrict__ W2pp,
    const float* __restrict__ Wm1, const float* __restrict__ bm1,
    const float* __restrict__ Wm2, const float* __restrict__ bm2,
    float* __restrict__ out) {
  __shared__ __align__(16) uint32_t s_H[4096];      // 16 KB packed H (content-swizzled)
  __shared__ __align__(16) uint32_t s_kdp[128];
  __shared__ int   s_seli[128];
  __shared__ float s_ybias[16];
  __shared__ float s_part[4][4][16];
  __shared__ float s_y[64];
  __shared__ float s_z[256];

  const int tid  = threadIdx.x;
  const int lane = tid & 63;
  const int wv   = tid >> 6;
  const int q    = blockIdx.x >> 2;
  const int sub  = blockIdx.x & 3;
  const int grp  = lane >> 4, m16 = lane & 15;

  if (tid < 128) s_seli[tid] = seli_ws[q * 128 + tid];
  if (tid >= 128 && tid < 256) s_kdp[tid - 128] = kdp[q * 128 + (tid - 128)];
  if (tid < 16) s_ybias[tid] = ybias_ws[q * 16 + tid];

  // H DMA: 4 rounds, linear LDS dest (content pre-swizzled at source by sel)
  const uint32_t* Hq = Hc + (size_t)q * 4096;
#pragma unroll
  for (int hc = 0; hc < 4; ++hc)
    gload_lds16(Hq + hc * 1024 + tid * 4, s_H + hc * 1024 + wv * 256);

  asm volatile("s_waitcnt vmcnt(0) lgkmcnt(0)\n\ts_barrier" ::: "memory");

  // per-lane gather base: bt = sub*4+wv, col = m16 (+ nt*16)
  const uint32_t* xbase = xs + ((size_t)(sub * 4 + wv) * V_PTS) * 32 + m16;

  floatx4 acc[3][2];
#pragma unroll
  for (int a = 0; a < 3; ++a)
#pragma unroll
    for (int b = 0; b < 2; ++b) acc[a][b] = (floatx4){0.f, 0.f, 0.f, 0.f};

  int va[8], vb[8];
  uint32_t ba[16], bb[16];

#define LOADV(CH, V)                                                          \
  _Pragma("unroll") for (int i = 0; i < 8; ++i)                               \
    V[i] = s_seli[(CH) * 32 + grp * 8 + i];
#define LOADB(V, B)                                                           \
  _Pragma("unroll") for (int i = 0; i < 8; ++i) {                             \
    const uint32_t* p = xbase + (size_t)V[i] * 32;                            \
    B[i] = p[0]; B[8 + i] = p[16];                                            \
  }

#define KBODY(CH, B)                                                           \
  {                                                                            \
    FragU Ah0, Al0, Ah1, Al1, Ah2, Al2;                                        \
    {                                                                          \
      const int swz = (m16 & 7) << 2;                                          \
      const uint32_t* h0 = s_H + (CH) * 1024 + m16 * 32;                       \
      const uint32_t* h1 = s_H + (CH) * 1024 + (16 + m16) * 32;                \
      const uint4 a0 = *(const uint4*)(h0 + ((grp * 8) ^ swz));                \
      const uint4 a1 = *(const uint4*)(h0 + ((grp * 8 + 4) ^ swz));            \
      const uint4 b0 = *(const uint4*)(h1 + ((grp * 8) ^ swz));                \
      const uint4 b1 = *(const uint4*)(h1 + ((grp * 8 + 4) ^ swz));            \
      const uint4 c0 = *(const uint4*)(s_kdp + (CH) * 32 + grp * 8);           \
      const uint4 c1 = *(const uint4*)(s_kdp + (CH) * 32 + grp * 8 + 4);       \
      buildfrag(a0, a1, Ah0, Al0);                                             \
      buildfrag(b0, b1, Ah1, Al1);                                             \
      buildfrag(c0, c1, Ah2, Al2);                                             \
      if (m16 != 0) {                                                          \
        _Pragma("unroll") for (int t = 0; t < 4; ++t) {                        \
          Ah2.u[t] = 0; Al2.u[t] = 0;                                          \
        }                                                                      \
      }                                                                        \
    }                                                                          \
    _Pragma("unroll") for (int nt = 0; nt < 2; ++nt) {                         \
      FragU Bh, Bl;                                                            \
      _Pragma("unroll") for (int t = 0; t < 4; ++t) {                          \
        Bh.u[t] = __builtin_amdgcn_perm(B[nt * 8 + 2 * t + 1], B[nt * 8 + 2 * t], 0x07060302u); \
        Bl.u[t] = __builtin_amdgcn_perm(B[nt * 8 + 2 * t + 1], B[nt * 8 + 2 * t], 0x05040100u); \
      }                                                                        \
      acc[0][nt] = __builtin_amdgcn_mfma_f32_16x16x32_bf16(Ah0.s, Bh.s, acc[0][nt], 0, 0, 0); \
      acc[0][nt] = __builtin_amdgcn_mfma_f32_16x16x32_bf16(Al0.s, Bh.s, acc[0][nt], 0, 0, 0); \
      acc[0][nt] = __builtin_amdgcn_mfma_f32_16x16x32_bf16(Ah0.s, Bl.s, acc[0][nt], 0, 0, 0); \
      acc[1][nt] = __builtin_amdgcn_mfma_f32_16x16x32_bf16(Ah1.s, Bh.s, acc[1][nt], 0, 0, 0); \
      acc[1][nt] = __builtin_amdgcn_mfma_f32_16x16x32_bf16(Al1.s, Bh.s, acc[1][nt], 0, 0, 0); \
      acc[1][nt] = __builtin_amdgcn_mfma_f32_16x16x32_bf16(Ah1.s, Bl.s, acc[1][nt], 0, 0, 0); \
      acc[2][nt] = __builtin_amdgcn_mfma_f32_16x16x32_bf16(Ah2.s, Bh.s, acc[2][nt], 0, 0, 0); \
      acc[2][nt] = __builtin_amdgcn_mfma_f32_16x16x32_bf16(Al2.s, Bh.s, acc[2][nt], 0, 0, 0); \
      acc[2][nt] = __builtin_amdgcn_mfma_f32_16x16x32_bf16(Ah2.s, Bl.s, acc[2][nt], 0, 0, 0); \
    }                                                                          \
  }

  LOADV(0, va); LOADB(va, ba);
  LOADV(1, vb); LOADB(vb, bb);
  KBODY(0, ba);
  LOADV(2, va); LOADB(va, ba);
  KBODY(1, bb);
  LOADV(3, vb); LOADB(vb, bb);
  KBODY(2, ba);
  KBODY(3, bb);
#undef KBODY
#undef LOADB
#undef LOADV

  // ---- epilogue: yac[d] accumulates ALL (nt, j) contributions for this lane's columns
  float yac[16];
#pragma unroll
  for (int e = 0; e < 16; ++e) yac[e] = 0.0f;
#pragma unroll
  for (int nt = 0; nt < 2; ++nt) {
    const int cp = nt * 16 + m16;
#pragma unroll
    for (int pp = 0; pp < 5; ++pp) {
      int j2; float g0, g1;
      if      (pp == 0) { j2 = grp * 2;         g0 = acc[0][nt][0]; g1 = acc[0][nt][1]; }
      else if (pp == 1) { j2 = grp * 2 + 1;     g0 = acc[0][nt][2]; g1 = acc[0][nt][3]; }
      else if (pp == 2) { j2 = 8 + grp * 2;     g0 = acc[1][nt][0]; g1 = acc[1][nt][1]; }
      else if (pp == 3) { j2 = 8 + grp * 2 + 1; g0 = acc[1][nt][2]; g1 = acc[1][nt][3]; }
      else              { j2 = 16;              g0 = acc[2][nt][0]; g1 = acc[2][nt][1]; }
      WU gw; gw.h.x = (_Float16)g0; gw.h.y = (_Float16)g1;   // RNE
      const uint4* w4 = (const uint4*)(W2pp + ((j2 * 32 + cp) << 4));
#pragma unroll
      for (int e = 0; e < 4; ++e) {
        const uint4 ww = w4[e];
        WU wa, wb, wc, wd; wa.u = ww.x; wb.u = ww.y; wc.u = ww.z; wd.u = ww.w;
        FDOT2(gw.h, wa.h, yac[e * 4 + 0]);
        FDOT2(gw.h, wb.h, yac[e * 4 + 1]);
        FDOT2(gw.h, wc.h, yac[e * 4 + 2]);
        FDOT2(gw.h, wd.h, yac[e * 4 + 3]);
      }
    }
  }
  // reduce over the 16 m16-lanes (lane bits 0..3)
#pragma unroll
  for (int m = 1; m <= 8; m <<= 1)
#pragma unroll
    for (int e = 0; e < 16; ++e) yac[e] += __shfl_xor(yac[e], m, 64);
  if (m16 == 0) {
#pragma unroll
    for (int e = 0; e < 16; ++e) s_part[wv][grp][e] = yac[e];   // exactly 16 floats
  }
  __syncthreads();

  if (tid < 64) {
    const int btl = tid >> 4, d = tid & 15;
    float y = s_part[btl][0][d] + s_part[btl][1][d] + s_part[btl][2][d] + s_part[btl][3][d];
    y += s_ybias[d];
    s_y[tid] = gelu_erf(y);
  }
  __syncthreads();
  {
    const int btl = tid >> 6, h = tid & 63;
    float s = bm1[h];
#pragma unroll
    for (int d2 = 0; d2 < 16; ++d2) s = fmaf(s_y[btl * 16 + d2], Wm1[d2 * 64 + h], s);
    s_z[btl * 64 + h] = gelu_erf(s);
  }
  __syncthreads();
  if (tid < 64) {
    const int btl = tid >> 4, d = tid & 15;
    float o = bm2[d];
#pragma unroll
    for (int h = 0; h < 64; ++h) o = fmaf(s_z[btl * 64 + h], Wm2[h * 16 + d], o);
    o += s_y[tid];
    out[((size_t)(sub * 4 + btl) * NQ + q) * 16 + d] = o;
  }
}

extern "C" void kernel_launch(void* const* d_in, const int* in_sizes, int n_in,
                              void* d_out, int out_size, void* d_ws, size_t ws_size,
                              hipStream_t stream) {
  const float* x    = (const float*)d_in[0];
  const float* pos  = (const float*)d_in[1];
  const float* qpos = (const float*)d_in[2];
  const float* qmw  = (const float*)d_in[3];
  const float* qmo  = (const float*)d_in[4];
  const float* Wl   = (const float*)d_in[5];
  const float* bl   = (const float*)d_in[6];
  const float* Brff = (const float*)d_in[7];
  const float* W1   = (const float*)d_in[8];
  const float* b1   = (const float*)d_in[9];
  const float* W2   = (const float*)d_in[10];
  const float* filt = (const float*)d_in[11];
  const float* bo   = (const float*)d_in[12];
  const float* Wm1  = (const float*)d_in[13];
  const float* bm1  = (const float*)d_in[14];
  const float* Wm2  = (const float*)d_in[15];
  const float* bm2  = (const float*)d_in[16];
  float* out = (float*)d_out;

  char* ws = (char*)d_ws;
  int*      seli_ws  = (int*)(ws + 0);               // 524,288 B
  uint32_t* Hc_ws    = (uint32_t*)(ws + 524288);     // 16,777,216 B
  uint32_t* kdp_ws   = (uint32_t*)(ws + 17301504);   // 524,288 B
  float*    ybias_ws = (float*)(ws + 17825792);      // 65,536 B
  float*    W2b_ws   = (float*)(ws + 17891328);      // 2,112 B
  uint32_t* W2pp_ws  = (uint32_t*)(ws + 17893440);   // 34,816 B
  uint32_t* xs_ws    = (uint32_t*)(ws + 17928256);   // 16,777,216 B (total ~34.7 MB)

  hipLaunchKernelGGL(aux_kernel, dim3(1041), dim3(256), 0, stream,
                     x, Wl, bl, W2, filt, xs_ws, W2pp_ws, W2b_ws);
  hipLaunchKernelGGL(sel_kernel, dim3(NQ), dim3(256), 0, stream,
                     pos, qpos, qmw, qmo, Brff, W1, b1, bo, W2b_ws,
                     seli_ws, Hc_ws, kdp_ws, ybias_ws, out);
  hipLaunchKernelGGL(main_kernel, dim3(4096), dim3(256), 0, stream,
                     xs_ws, seli_ws, Hc_ws, kdp_ws, ybias_ws, W2pp_ws,
                     Wm1, bm1, Wm2, bm2, out);
}